// Round 1
// baseline (1664.798 us; speedup 1.0000x reference)
//
#include <hip/hip_runtime.h>
#include <math.h>

#define IN_CH 512
#define HID 128
#define NCLASS 40

// ---------------- degree / norm ----------------
__global__ void k_init_deg(float* deg, int n) {
    int i = blockIdx.x * blockDim.x + threadIdx.x;
    if (i < n) deg[i] = 1.0f;  // self-loop contributes 1
}

__global__ void k_count_deg(const int* __restrict__ dst, int E, float* deg) {
    int i = blockIdx.x * blockDim.x + threadIdx.x;
    if (i < E) atomicAdd(&deg[dst[i]], 1.0f);
}

__global__ void k_make_dinv(float* deg, int n) {
    int i = blockIdx.x * blockDim.x + threadIdx.x;
    if (i < n) deg[i] = rsqrtf(deg[i]);  // deg >= 1 always
}

// ---------------- GEMM1: [M,512] @ [512,128] -> [M,128] ----------------
#define BM 64
#define BN 128
#define BK 32
__global__ __launch_bounds__(256) void k_gemm1(const float* __restrict__ X,
                                               const float* __restrict__ W,
                                               float* __restrict__ H, int M) {
    __shared__ float As[BK][BM + 1];    // [k][m], +1 pad breaks bank conflicts
    __shared__ float Bs[BK][BN + 4];    // [k][n], +4 keeps 16B row alignment
    int bm = blockIdx.x * BM;
    int tid = threadIdx.x;
    int tx = tid & 15;   // col group: cols tx*8 .. +7
    int ty = tid >> 4;   // row group: rows ty*4 .. +3
    float acc[4][8] = {};

    for (int k0 = 0; k0 < IN_CH; k0 += BK) {
        // stage A tile (64x32): 512 float4 loads, 2 per thread
        for (int l = tid; l < (BM * BK) / 4; l += 256) {
            int r = l / (BK / 4);          // row in tile
            int cc = (l % (BK / 4)) * 4;   // k offset
            int gm = bm + r;
            float4 v = make_float4(0.f, 0.f, 0.f, 0.f);
            if (gm < M) v = *(const float4*)&X[(size_t)gm * IN_CH + k0 + cc];
            As[cc + 0][r] = v.x; As[cc + 1][r] = v.y;
            As[cc + 2][r] = v.z; As[cc + 3][r] = v.w;
        }
        // stage B tile (32x128): 1024 float4 loads, 4 per thread
        for (int l = tid; l < (BK * BN) / 4; l += 256) {
            int r = l / (BN / 4);
            int cc = (l % (BN / 4)) * 4;
            *(float4*)&Bs[r][cc] = *(const float4*)&W[(size_t)(k0 + r) * BN + cc];
        }
        __syncthreads();
        #pragma unroll
        for (int k = 0; k < BK; ++k) {
            float a[4], b[8];
            #pragma unroll
            for (int i = 0; i < 4; ++i) a[i] = As[k][ty * 4 + i];
            #pragma unroll
            for (int j = 0; j < 8; ++j) b[j] = Bs[k][tx * 8 + j];
            #pragma unroll
            for (int i = 0; i < 4; ++i)
                #pragma unroll
                for (int j = 0; j < 8; ++j) acc[i][j] += a[i] * b[j];
        }
        __syncthreads();
    }
    #pragma unroll
    for (int i = 0; i < 4; ++i) {
        int gm = bm + ty * 4 + i;
        if (gm < M) {
            #pragma unroll
            for (int j = 0; j < 8; ++j)
                H[(size_t)gm * BN + tx * 8 + j] = acc[i][j];
        }
    }
}

// ---------------- edge scatter, layer 1 (128 ch) ----------------
__global__ void k_scatter1(const int* __restrict__ src, const int* __restrict__ dst,
                           const float* __restrict__ dinv, const float* __restrict__ h1,
                           float* agg, long long total) {
    long long idx = (long long)blockIdx.x * blockDim.x + threadIdx.x;
    if (idx >= total) return;
    int e = (int)(idx >> 7);
    int c = (int)(idx & 127);
    int s = src[e], d = dst[e];
    float nrm = dinv[s] * dinv[d];
    atomicAdd(&agg[(size_t)d * HID + c], h1[(size_t)s * HID + c] * nrm);
}

// ---------------- self-loop + bias + relu ----------------
__global__ void k_relu_bias(float* agg1, const float* __restrict__ h1,
                            const float* __restrict__ dinv, const float* __restrict__ b1,
                            long long total) {
    long long idx = (long long)blockIdx.x * blockDim.x + threadIdx.x;
    if (idx >= total) return;
    int m = (int)(idx >> 7);
    int c = (int)(idx & 127);
    float di = dinv[m];
    float v = agg1[idx] + h1[idx] * di * di + b1[c];
    agg1[idx] = v > 0.f ? v : 0.f;
}

// ---------------- GEMM2: [M,128] @ [128,40] -> [M,40] ----------------
__global__ __launch_bounds__(64) void k_gemm2(const float* __restrict__ Hin,
                                              const float* __restrict__ W2,
                                              float* __restrict__ H2, int M) {
    __shared__ float hs[HID];
    int m = blockIdx.x;
    int t = threadIdx.x;  // 64
    hs[t] = Hin[(size_t)m * HID + t];
    hs[t + 64] = Hin[(size_t)m * HID + t + 64];
    __syncthreads();
    if (t < NCLASS) {
        float acc = 0.f;
        #pragma unroll 8
        for (int k = 0; k < HID; ++k) acc += hs[k] * W2[k * NCLASS + t];
        H2[(size_t)m * NCLASS + t] = acc;
    }
}

// ---------------- edge scatter, layer 2 (40 ch) ----------------
__global__ void k_scatter2(const int* __restrict__ src, const int* __restrict__ dst,
                           const float* __restrict__ dinv, const float* __restrict__ h2,
                           float* agg, long long total) {
    long long idx = (long long)blockIdx.x * blockDim.x + threadIdx.x;
    if (idx >= total) return;
    unsigned int u = (unsigned int)idx;
    int e = (int)(u / NCLASS);    // total = E*40 < 2^31 -> fits u32
    int c = (int)(u % NCLASS);
    int s = src[e], d = dst[e];
    float nrm = dinv[s] * dinv[d];
    atomicAdd(&agg[(size_t)d * NCLASS + c], h2[(size_t)s * NCLASS + c] * nrm);
}

// ---------------- self-loop + bias + log_softmax ----------------
__global__ __launch_bounds__(64) void k_final(const float* __restrict__ agg2,
                                              const float* __restrict__ h2,
                                              const float* __restrict__ dinv,
                                              const float* __restrict__ b2,
                                              float* __restrict__ out, int M) {
    int m = blockIdx.x;
    int t = threadIdx.x;  // 64 lanes, 40 active
    float val = 0.f, v = -INFINITY;
    if (t < NCLASS) {
        float di = dinv[m];
        size_t i = (size_t)m * NCLASS + t;
        val = agg2[i] + h2[i] * di * di + b2[t];
        v = val;
    }
    #pragma unroll
    for (int off = 32; off; off >>= 1) v = fmaxf(v, __shfl_xor(v, off));
    float ex = (t < NCLASS) ? expf(val - v) : 0.f;
    #pragma unroll
    for (int off = 32; off; off >>= 1) ex += __shfl_xor(ex, off);
    float lse = v + logf(ex);
    if (t < NCLASS) out[(size_t)m * NCLASS + t] = val - lse;
}

extern "C" void kernel_launch(void* const* d_in, const int* in_sizes, int n_in,
                              void* d_out, int out_size, void* d_ws, size_t ws_size,
                              hipStream_t stream) {
    const float* x  = (const float*)d_in[0];
    const int*   ei = (const int*)d_in[1];
    const float* W1 = (const float*)d_in[2];
    const float* b1 = (const float*)d_in[3];
    const float* W2 = (const float*)d_in[4];
    const float* b2 = (const float*)d_in[5];
    float* out = (float*)d_out;

    const int N = in_sizes[0] / IN_CH;       // 100000
    const int E = in_sizes[1] / 2;           // 1600000
    const int* src = ei;
    const int* dst = ei + E;

    // workspace layout (floats)
    float* ws = (float*)d_ws;
    size_t o_dinv = 0;
    size_t o_h1   = ((size_t)N + 127) / 128 * 128;       // after dinv
    size_t o_agg1 = o_h1 + (size_t)N * HID;
    // after relu consumes h1, its region is reused for h2 + agg2
    size_t o_h2   = o_h1;
    size_t o_agg2 = o_h1 + (size_t)N * NCLASS;

    float* dinv = ws + o_dinv;
    float* h1   = ws + o_h1;
    float* agg1 = ws + o_agg1;
    float* h2   = ws + o_h2;
    float* agg2 = ws + o_agg2;

    // 1) degree + dinv
    k_init_deg<<<(N + 255) / 256, 256, 0, stream>>>(dinv, N);
    k_count_deg<<<(E + 255) / 256, 256, 0, stream>>>(dst, E, dinv);
    k_make_dinv<<<(N + 255) / 256, 256, 0, stream>>>(dinv, N);

    // 2) zero agg1 (safe: doesn't overlap h1)
    hipMemsetAsync(agg1, 0, (size_t)N * HID * sizeof(float), stream);

    // 3) GEMM1
    k_gemm1<<<(N + BM - 1) / BM, 256, 0, stream>>>(x, W1, h1, N);

    // 4) scatter layer 1
    long long tot1 = (long long)E * HID;
    k_scatter1<<<(unsigned int)((tot1 + 255) / 256), 256, 0, stream>>>(
        src, dst, dinv, h1, agg1, tot1);

    // 5) self-loop + bias + relu (agg1 -> h, in place); h1 dead afterwards
    long long totr = (long long)N * HID;
    k_relu_bias<<<(unsigned int)((totr + 255) / 256), 256, 0, stream>>>(
        agg1, h1, dinv, b1, totr);

    // 6) zero agg2 (lives in old h1 region — only safe now)
    hipMemsetAsync(agg2, 0, (size_t)N * NCLASS * sizeof(float), stream);

    // 7) GEMM2 (reads agg1=h, writes h2 in old h1 region)
    k_gemm2<<<N, 64, 0, stream>>>(agg1, W2, h2, N);

    // 8) scatter layer 2
    long long tot2 = (long long)E * NCLASS;
    k_scatter2<<<(unsigned int)((tot2 + 255) / 256), 256, 0, stream>>>(
        src, dst, dinv, h2, agg2, tot2);

    // 9) self-loop + bias + log_softmax -> out
    k_final<<<N, 64, 0, stream>>>(agg2, h2, dinv, b2, out, N);
}

// Round 2
// 985.169 us; speedup vs baseline: 1.6899x; 1.6899x over previous
//
#include <hip/hip_runtime.h>
#include <math.h>

#define IN_CH 512
#define HID 128
#define NCLASS 40
#define SCAN_CHUNK 2048   // per-block scan chunk: 256 threads x 8

// ---------------- degree count (int atomics, 1.6M) ----------------
__global__ void k_count(const int* __restrict__ dst, int E, int* __restrict__ cnt) {
    int i = blockIdx.x * blockDim.x + threadIdx.x;
    if (i < E) atomicAdd(&cnt[dst[i]], 1);
}

__global__ void k_dinv(const int* __restrict__ cnt, float* __restrict__ dinv, int n) {
    int i = blockIdx.x * blockDim.x + threadIdx.x;
    if (i < n) dinv[i] = rsqrtf((float)cnt[i] + 1.0f);  // +1 self-loop
}

// ---------------- exclusive scan of cnt -> rowptr (3 kernels) ----------------
__global__ __launch_bounds__(256) void k_scan_local(const int* __restrict__ cnt,
                                                    int* __restrict__ rowptr,
                                                    int* __restrict__ blocksum, int n) {
    __shared__ int ssum[256];
    int b = blockIdx.x, t = threadIdx.x;
    int base = b * SCAN_CHUNK + t * 8;
    int v[8], s = 0;
    #pragma unroll
    for (int i = 0; i < 8; ++i) {
        int idx = base + i;
        v[i] = (idx < n) ? cnt[idx] : 0;
        s += v[i];
    }
    ssum[t] = s;
    __syncthreads();
    // Hillis-Steele inclusive scan over 256 thread-sums
    for (int off = 1; off < 256; off <<= 1) {
        int x = (t >= off) ? ssum[t - off] : 0;
        __syncthreads();
        ssum[t] += x;
        __syncthreads();
    }
    int run = ssum[t] - s;  // exclusive prefix of this thread's chunk
    #pragma unroll
    for (int i = 0; i < 8; ++i) {
        int idx = base + i;
        if (idx < n) rowptr[idx] = run;
        run += v[i];
    }
    if (t == 255) blocksum[b] = ssum[255];
}

__global__ void k_scan_blocksums(int* blocksum, int nb) {
    if (threadIdx.x == 0 && blockIdx.x == 0) {
        int acc = 0;
        for (int i = 0; i < nb; ++i) { int v = blocksum[i]; blocksum[i] = acc; acc += v; }
    }
}

__global__ void k_scan_add(int* __restrict__ rowptr, int* __restrict__ cursor,
                           const int* __restrict__ blocksum, int n) {
    int i = blockIdx.x * blockDim.x + threadIdx.x;
    if (i < n) {
        int r = rowptr[i] + blocksum[i / SCAN_CHUNK];
        rowptr[i] = r;
        cursor[i] = r;
    }
}

// ---------------- CSR fill: col[pos] = src, grouped by dst ----------------
__global__ void k_fill(const int* __restrict__ src, const int* __restrict__ dst,
                       int* __restrict__ cursor, int* __restrict__ col, int E) {
    int e = blockIdx.x * blockDim.x + threadIdx.x;
    if (e < E) {
        int p = atomicAdd(&cursor[dst[e]], 1);
        col[p] = src[e];
    }
    // after this kernel: cursor[i] == row end
}

// ---------------- GEMM1: [M,512] @ [512,128] -> [M,128] ----------------
#define BM 64
#define BN 128
#define BK 32
__global__ __launch_bounds__(256) void k_gemm1(const float* __restrict__ X,
                                               const float* __restrict__ W,
                                               float* __restrict__ H, int M) {
    __shared__ float As[BK][BM + 1];
    __shared__ float Bs[BK][BN + 4];
    int bm = blockIdx.x * BM;
    int tid = threadIdx.x;
    int tx = tid & 15;
    int ty = tid >> 4;
    float acc[4][8] = {};

    for (int k0 = 0; k0 < IN_CH; k0 += BK) {
        for (int l = tid; l < (BM * BK) / 4; l += 256) {
            int r = l / (BK / 4);
            int cc = (l % (BK / 4)) * 4;
            int gm = bm + r;
            float4 v = make_float4(0.f, 0.f, 0.f, 0.f);
            if (gm < M) v = *(const float4*)&X[(size_t)gm * IN_CH + k0 + cc];
            As[cc + 0][r] = v.x; As[cc + 1][r] = v.y;
            As[cc + 2][r] = v.z; As[cc + 3][r] = v.w;
        }
        for (int l = tid; l < (BK * BN) / 4; l += 256) {
            int r = l / (BN / 4);
            int cc = (l % (BN / 4)) * 4;
            *(float4*)&Bs[r][cc] = *(const float4*)&W[(size_t)(k0 + r) * BN + cc];
        }
        __syncthreads();
        #pragma unroll
        for (int k = 0; k < BK; ++k) {
            float a[4], b[8];
            #pragma unroll
            for (int i = 0; i < 4; ++i) a[i] = As[k][ty * 4 + i];
            #pragma unroll
            for (int j = 0; j < 8; ++j) b[j] = Bs[k][tx * 8 + j];
            #pragma unroll
            for (int i = 0; i < 4; ++i)
                #pragma unroll
                for (int j = 0; j < 8; ++j) acc[i][j] += a[i] * b[j];
        }
        __syncthreads();
    }
    #pragma unroll
    for (int i = 0; i < 4; ++i) {
        int gm = bm + ty * 4 + i;
        if (gm < M) {
            #pragma unroll
            for (int j = 0; j < 8; ++j)
                H[(size_t)gm * BN + tx * 8 + j] = acc[i][j];
        }
    }
}

// ---------------- layer-1 aggregation: gather CSR + self-loop + bias + relu ----
// one wave per node; lane t owns channels {2t, 2t+1} as float2
__global__ __launch_bounds__(64) void k_agg1(const int* __restrict__ rowptr,
                                             const int* __restrict__ rowend,
                                             const int* __restrict__ col,
                                             const float* __restrict__ dinv,
                                             const float2* __restrict__ h1,
                                             const float* __restrict__ b1,
                                             float2* __restrict__ h, int N) {
    int m = blockIdx.x;
    int t = threadIdx.x;
    float dm = dinv[m];
    float2 acc = h1[(size_t)m * 64 + t];       // self loop
    float sw = dm * dm;
    acc.x *= sw; acc.y *= sw;
    int j = rowptr[m], jend = rowend[m];
    for (; j < jend; ++j) {
        int s = col[j];
        float nrm = dinv[s] * dm;
        float2 v = h1[(size_t)s * 64 + t];
        acc.x += v.x * nrm;
        acc.y += v.y * nrm;
    }
    float2 bb = ((const float2*)b1)[t];
    acc.x = fmaxf(acc.x + bb.x, 0.f);
    acc.y = fmaxf(acc.y + bb.y, 0.f);
    h[(size_t)m * 64 + t] = acc;
}

// ---------------- GEMM2: [M,128] @ [128,40] -> [M,40] ----------------
__global__ __launch_bounds__(64) void k_gemm2(const float* __restrict__ Hin,
                                              const float* __restrict__ W2,
                                              float* __restrict__ H2, int M) {
    __shared__ float hs[HID];
    int m = blockIdx.x;
    int t = threadIdx.x;
    hs[t] = Hin[(size_t)m * HID + t];
    hs[t + 64] = Hin[(size_t)m * HID + t + 64];
    __syncthreads();
    if (t < NCLASS) {
        float acc = 0.f;
        #pragma unroll 8
        for (int k = 0; k < HID; ++k) acc += hs[k] * W2[k * NCLASS + t];
        H2[(size_t)m * NCLASS + t] = acc;
    }
}

// ------- layer-2 aggregation + self-loop + bias + log_softmax, fused -------
__global__ __launch_bounds__(64) void k_agg2_final(const int* __restrict__ rowptr,
                                                   const int* __restrict__ rowend,
                                                   const int* __restrict__ col,
                                                   const float* __restrict__ dinv,
                                                   const float* __restrict__ h2,
                                                   const float* __restrict__ b2,
                                                   float* __restrict__ out, int N) {
    int m = blockIdx.x;
    int t = threadIdx.x;   // 64 lanes, 40 active for channel work
    float dm = dinv[m];
    float val = 0.f;
    if (t < NCLASS) val = h2[(size_t)m * NCLASS + t] * dm * dm;  // self loop
    int jend = rowend[m];
    for (int j = rowptr[m]; j < jend; ++j) {
        int s = col[j];
        float nrm = dinv[s] * dm;
        if (t < NCLASS) val += h2[(size_t)s * NCLASS + t] * nrm;
    }
    if (t < NCLASS) val += b2[t];
    float v = (t < NCLASS) ? val : -INFINITY;
    #pragma unroll
    for (int off = 32; off; off >>= 1) v = fmaxf(v, __shfl_xor(v, off));
    float ex = (t < NCLASS) ? expf(val - v) : 0.f;
    #pragma unroll
    for (int off = 32; off; off >>= 1) ex += __shfl_xor(ex, off);
    float lse = v + logf(ex);
    if (t < NCLASS) out[(size_t)m * NCLASS + t] = val - lse;
}

extern "C" void kernel_launch(void* const* d_in, const int* in_sizes, int n_in,
                              void* d_out, int out_size, void* d_ws, size_t ws_size,
                              hipStream_t stream) {
    const float* x  = (const float*)d_in[0];
    const int*   ei = (const int*)d_in[1];
    const float* W1 = (const float*)d_in[2];
    const float* b1 = (const float*)d_in[3];
    const float* W2 = (const float*)d_in[4];
    const float* b2 = (const float*)d_in[5];
    float* out = (float*)d_out;

    const int N = in_sizes[0] / IN_CH;   // 100000
    const int E = in_sizes[1] / 2;       // 1600000
    const int* src = ei;
    const int* dst = ei + E;

    const int NB_SCAN = (N + SCAN_CHUNK - 1) / SCAN_CHUNK;   // 49

    // workspace layout (4-byte words)
    size_t Npad = ((size_t)N + 127) / 128 * 128;
    float* ws = (float*)d_ws;
    float* dinv    = ws;                         // N floats
    int*   cnt     = (int*)(ws + Npad);          // N ints
    int*   rowptr  = (int*)(ws + 2 * Npad);      // N ints (row start)
    int*   cursor  = (int*)(ws + 3 * Npad);      // N ints (becomes row end)
    int*   bsum    = (int*)(ws + 4 * Npad);      // <=128 ints
    int*   col     = (int*)(ws + 4 * Npad + 128);            // E ints
    size_t o_h1    = 4 * Npad + 128 + (size_t)E;
    float* h1      = ws + o_h1;                  // N*128
    float* h       = ws + o_h1 + (size_t)N * HID; // N*128
    float* h2      = h1;                          // reuse h1 region (dead after agg1)

    // ---- CSR build ----
    hipMemsetAsync(cnt, 0, (size_t)N * sizeof(int), stream);
    k_count<<<(E + 255) / 256, 256, 0, stream>>>(dst, E, cnt);
    k_dinv<<<(N + 255) / 256, 256, 0, stream>>>(cnt, dinv, N);
    k_scan_local<<<NB_SCAN, 256, 0, stream>>>(cnt, rowptr, bsum, N);
    k_scan_blocksums<<<1, 64, 0, stream>>>(bsum, NB_SCAN);
    k_scan_add<<<(N + 255) / 256, 256, 0, stream>>>(rowptr, cursor, bsum, N);
    k_fill<<<(E + 255) / 256, 256, 0, stream>>>(src, dst, cursor, col, E);

    // ---- layer 1 ----
    k_gemm1<<<(N + BM - 1) / BM, 256, 0, stream>>>(x, W1, h1, N);
    k_agg1<<<N, 64, 0, stream>>>(rowptr, cursor, col, dinv, (const float2*)h1, b1,
                                 (float2*)h, N);

    // ---- layer 2 ----
    k_gemm2<<<N, 64, 0, stream>>>(h, W2, h2, N);
    k_agg2_final<<<N, 64, 0, stream>>>(rowptr, cursor, col, dinv, h2, b2, out, N);
}

// Round 3
// 859.349 us; speedup vs baseline: 1.9373x; 1.1464x over previous
//
#include <hip/hip_runtime.h>
#include <math.h>

#define IN_CH 512
#define HID 128
#define NCLASS 40
#define SCAN_CHUNK 2048   // per-block scan chunk: 256 threads x 8

typedef __attribute__((ext_vector_type(8))) short short8;
typedef __attribute__((ext_vector_type(4))) float float4v;

static __device__ inline ushort f2bf(float f) {
    // round-to-nearest-even fp32 -> bf16 (inputs are finite; NaN path not needed)
    unsigned int u = __float_as_uint(f);
    u += 0x7fffu + ((u >> 16) & 1u);
    return (ushort)(u >> 16);
}

// ---------------- degree count (int atomics, 1.6M) ----------------
__global__ void k_count(const int* __restrict__ dst, int E, int* __restrict__ cnt) {
    int i = blockIdx.x * blockDim.x + threadIdx.x;
    if (i < E) atomicAdd(&cnt[dst[i]], 1);
}

__global__ void k_dinv(const int* __restrict__ cnt, float* __restrict__ dinv, int n) {
    int i = blockIdx.x * blockDim.x + threadIdx.x;
    if (i < n) dinv[i] = rsqrtf((float)cnt[i] + 1.0f);  // +1 self-loop
}

// ---------------- exclusive scan of cnt -> rowptr ----------------
__global__ __launch_bounds__(256) void k_scan_local(const int* __restrict__ cnt,
                                                    int* __restrict__ rowptr,
                                                    int* __restrict__ blocksum, int n) {
    __shared__ int ssum[256];
    int b = blockIdx.x, t = threadIdx.x;
    int base = b * SCAN_CHUNK + t * 8;
    int v[8], s = 0;
    #pragma unroll
    for (int i = 0; i < 8; ++i) {
        int idx = base + i;
        v[i] = (idx < n) ? cnt[idx] : 0;
        s += v[i];
    }
    ssum[t] = s;
    __syncthreads();
    for (int off = 1; off < 256; off <<= 1) {
        int x = (t >= off) ? ssum[t - off] : 0;
        __syncthreads();
        ssum[t] += x;
        __syncthreads();
    }
    int run = ssum[t] - s;
    #pragma unroll
    for (int i = 0; i < 8; ++i) {
        int idx = base + i;
        if (idx < n) rowptr[idx] = run;
        run += v[i];
    }
    if (t == 255) blocksum[b] = ssum[255];
}

__global__ void k_scan_blocksums(int* blocksum, int nb) {
    if (threadIdx.x == 0 && blockIdx.x == 0) {
        int acc = 0;
        for (int i = 0; i < nb; ++i) { int v = blocksum[i]; blocksum[i] = acc; acc += v; }
    }
}

__global__ void k_scan_add(int* __restrict__ rowptr, int* __restrict__ cursor,
                           const int* __restrict__ blocksum, int n) {
    int i = blockIdx.x * blockDim.x + threadIdx.x;
    if (i < n) {
        int r = rowptr[i] + blocksum[i / SCAN_CHUNK];
        rowptr[i] = r;
        cursor[i] = r;
    }
}

// ---------------- CSR fill ----------------
__global__ void k_fill(const int* __restrict__ src, const int* __restrict__ dst,
                       int* __restrict__ cursor, int* __restrict__ col, int E) {
    int e = blockIdx.x * blockDim.x + threadIdx.x;
    if (e < E) {
        int p = atomicAdd(&cursor[dst[e]], 1);
        col[p] = src[e];
    }
}

// ---------------- W1 [512][128] fp32 -> W1t [128][512] bf16 ----------------
__global__ void k_w1t(const float* __restrict__ W1, ushort* __restrict__ W1t) {
    int i = blockIdx.x * blockDim.x + threadIdx.x;  // 128*512
    int n = i >> 9;
    int k = i & 511;
    W1t[i] = f2bf(W1[k * HID + n]);
}

// ---------------- GEMM1 (MFMA bf16): [M,512] @ [512,128] -> [M,128] fp32 ----
#define GBM 128
#define GBK 64
#define KP 72    // padded k-stride in LDS (bf16 elems): 144 B -> 2-way max conflict
__global__ __launch_bounds__(256) void k_gemm1_mfma(const float* __restrict__ X,
                                                    const ushort* __restrict__ W1t,
                                                    float* __restrict__ H, int M) {
    __shared__ ushort As[GBM * KP];   // A[m][k] bf16, 18432 B
    __shared__ ushort Bs[HID * KP];   // Bt[n][k] bf16, 18432 B
    int t = threadIdx.x;
    int bm = blockIdx.x * GBM;
    int wave = t >> 6;
    int lane = t & 63;
    int m0w = (wave >> 1) * 64;
    int n0w = (wave & 1) * 64;
    int lrow = lane & 15;
    int quad = lane >> 4;

    float4v acc[4][4];
    #pragma unroll
    for (int i = 0; i < 4; ++i)
        #pragma unroll
        for (int j = 0; j < 4; ++j) acc[i][j] = (float4v)(0.f);

    int ar = t >> 3;          // 0..31: row/n index base per pass
    int ak = (t & 7) * 8;     // k offset (8 elems = 16 B)

    for (int k0 = 0; k0 < IN_CH; k0 += GBK) {
        #pragma unroll
        for (int p = 0; p < 4; ++p) {
            int r = ar + 32 * p;
            int gm = bm + r;
            union { ushort u[8]; uint4 v; } pk;
            if (gm < M) {
                const float* gp = &X[(size_t)gm * IN_CH + k0 + ak];
                float4 f0 = *(const float4*)gp;
                float4 f1 = *(const float4*)(gp + 4);
                pk.u[0] = f2bf(f0.x); pk.u[1] = f2bf(f0.y);
                pk.u[2] = f2bf(f0.z); pk.u[3] = f2bf(f0.w);
                pk.u[4] = f2bf(f1.x); pk.u[5] = f2bf(f1.y);
                pk.u[6] = f2bf(f1.z); pk.u[7] = f2bf(f1.w);
            } else {
                pk.v = make_uint4(0, 0, 0, 0);
            }
            *(uint4*)&As[r * KP + ak] = pk.v;
            // B tile: straight bf16 copy from pre-transposed W1t[n][k]
            uint4 bv = *(const uint4*)&W1t[(size_t)r * IN_CH + k0 + ak];
            *(uint4*)&Bs[r * KP + ak] = bv;
        }
        __syncthreads();
        #pragma unroll
        for (int kk = 0; kk < GBK; kk += 32) {
            short8 af[4], bfr[4];
            #pragma unroll
            for (int i = 0; i < 4; ++i)
                af[i] = *(const short8*)&As[(m0w + i * 16 + lrow) * KP + kk + quad * 8];
            #pragma unroll
            for (int j = 0; j < 4; ++j)
                bfr[j] = *(const short8*)&Bs[(n0w + j * 16 + lrow) * KP + kk + quad * 8];
            #pragma unroll
            for (int i = 0; i < 4; ++i)
                #pragma unroll
                for (int j = 0; j < 4; ++j)
                    acc[i][j] = __builtin_amdgcn_mfma_f32_16x16x32_bf16(
                        af[i], bfr[j], acc[i][j], 0, 0, 0);
        }
        __syncthreads();
    }
    #pragma unroll
    for (int i = 0; i < 4; ++i) {
        #pragma unroll
        for (int r = 0; r < 4; ++r) {
            int gm = bm + m0w + i * 16 + quad * 4 + r;
            if (gm < M) {
                #pragma unroll
                for (int j = 0; j < 4; ++j)
                    H[(size_t)gm * HID + n0w + j * 16 + lrow] = acc[i][j][r];
            }
        }
    }
}

// ---------------- layer-1 aggregation (gather) + self-loop + bias + relu ----
__global__ __launch_bounds__(64) void k_agg1(const int* __restrict__ rowptr,
                                             const int* __restrict__ rowend,
                                             const int* __restrict__ col,
                                             const float* __restrict__ dinv,
                                             const float2* __restrict__ h1,
                                             const float* __restrict__ b1,
                                             float2* __restrict__ h, int N) {
    int m = blockIdx.x;
    int t = threadIdx.x;
    float dm = dinv[m];
    float2 acc = h1[(size_t)m * 64 + t];       // self loop
    float sw = dm * dm;
    acc.x *= sw; acc.y *= sw;
    int j = rowptr[m], jend = rowend[m];
    for (; j < jend; ++j) {
        int s = col[j];
        float nrm = dinv[s] * dm;
        float2 v = h1[(size_t)s * 64 + t];
        acc.x += v.x * nrm;
        acc.y += v.y * nrm;
    }
    float2 bb = ((const float2*)b1)[t];
    acc.x = fmaxf(acc.x + bb.x, 0.f);
    acc.y = fmaxf(acc.y + bb.y, 0.f);
    h[(size_t)m * 64 + t] = acc;
}

// ---------------- GEMM2: [M,128] @ [128,40] -> [M,40] ----------------
__global__ __launch_bounds__(64) void k_gemm2(const float* __restrict__ Hin,
                                              const float* __restrict__ W2,
                                              float* __restrict__ H2, int M) {
    __shared__ float hs[HID];
    int m = blockIdx.x;
    int t = threadIdx.x;
    hs[t] = Hin[(size_t)m * HID + t];
    hs[t + 64] = Hin[(size_t)m * HID + t + 64];
    __syncthreads();
    if (t < NCLASS) {
        float acc = 0.f;
        #pragma unroll 8
        for (int k = 0; k < HID; ++k) acc += hs[k] * W2[k * NCLASS + t];
        H2[(size_t)m * NCLASS + t] = acc;
    }
}

// ------- layer-2 aggregation + self-loop + bias + log_softmax ----------
__global__ __launch_bounds__(64) void k_agg2_final(const int* __restrict__ rowptr,
                                                   const int* __restrict__ rowend,
                                                   const int* __restrict__ col,
                                                   const float* __restrict__ dinv,
                                                   const float* __restrict__ h2,
                                                   const float* __restrict__ b2,
                                                   float* __restrict__ out, int N) {
    int m = blockIdx.x;
    int t = threadIdx.x;
    float dm = dinv[m];
    float val = 0.f;
    if (t < NCLASS) val = h2[(size_t)m * NCLASS + t] * dm * dm;
    int jend = rowend[m];
    for (int j = rowptr[m]; j < jend; ++j) {
        int s = col[j];
        float nrm = dinv[s] * dm;
        if (t < NCLASS) val += h2[(size_t)s * NCLASS + t] * nrm;
    }
    if (t < NCLASS) val += b2[t];
    float v = (t < NCLASS) ? val : -INFINITY;
    #pragma unroll
    for (int off = 32; off; off >>= 1) v = fmaxf(v, __shfl_xor(v, off));
    float ex = (t < NCLASS) ? expf(val - v) : 0.f;
    #pragma unroll
    for (int off = 32; off; off >>= 1) ex += __shfl_xor(ex, off);
    float lse = v + logf(ex);
    if (t < NCLASS) out[(size_t)m * NCLASS + t] = val - lse;
}

extern "C" void kernel_launch(void* const* d_in, const int* in_sizes, int n_in,
                              void* d_out, int out_size, void* d_ws, size_t ws_size,
                              hipStream_t stream) {
    const float* x  = (const float*)d_in[0];
    const int*   ei = (const int*)d_in[1];
    const float* W1 = (const float*)d_in[2];
    const float* b1 = (const float*)d_in[3];
    const float* W2 = (const float*)d_in[4];
    const float* b2 = (const float*)d_in[5];
    float* out = (float*)d_out;

    const int N = in_sizes[0] / IN_CH;   // 100000
    const int E = in_sizes[1] / 2;       // 1600000
    const int* src = ei;
    const int* dst = ei + E;

    const int NB_SCAN = (N + SCAN_CHUNK - 1) / SCAN_CHUNK;

    // workspace layout (4-byte words)
    size_t Npad = ((size_t)N + 127) / 128 * 128;
    float* ws = (float*)d_ws;
    float* dinv    = ws;                         // N floats
    int*   cnt     = (int*)(ws + Npad);          // N ints
    int*   rowptr  = (int*)(ws + 2 * Npad);      // N ints
    int*   cursor  = (int*)(ws + 3 * Npad);      // N ints (becomes row end)
    int*   bsum    = (int*)(ws + 4 * Npad);      // <=128 ints
    int*   col     = (int*)(ws + 4 * Npad + 128);            // E ints
    size_t o_h1    = 4 * Npad + 128 + (size_t)E;
    float* h1      = ws + o_h1;                   // N*128 fp32
    float* h       = ws + o_h1 + (size_t)N * HID; // N*128 fp32
    float* h2      = h1;                          // reuse (h1 dead after agg1)
    // W1t (128 KB bf16) aliases the start of `h` — dead before agg1 writes h
    ushort* W1t    = (ushort*)h;

    // ---- CSR build ----
    hipMemsetAsync(cnt, 0, (size_t)N * sizeof(int), stream);
    k_count<<<(E + 255) / 256, 256, 0, stream>>>(dst, E, cnt);
    k_dinv<<<(N + 255) / 256, 256, 0, stream>>>(cnt, dinv, N);
    k_scan_local<<<NB_SCAN, 256, 0, stream>>>(cnt, rowptr, bsum, N);
    k_scan_blocksums<<<1, 64, 0, stream>>>(bsum, NB_SCAN);
    k_scan_add<<<(N + 255) / 256, 256, 0, stream>>>(rowptr, cursor, bsum, N);
    k_fill<<<(E + 255) / 256, 256, 0, stream>>>(src, dst, cursor, col, E);

    // ---- layer 1: bf16 MFMA transform, then gather-aggregate ----
    k_w1t<<<(HID * IN_CH) / 256, 256, 0, stream>>>(W1, W1t);
    k_gemm1_mfma<<<(N + GBM - 1) / GBM, 256, 0, stream>>>(x, W1t, h1, N);
    k_agg1<<<N, 64, 0, stream>>>(rowptr, cursor, col, dinv, (const float2*)h1, b1,
                                 (float2*)h, N);

    // ---- layer 2 ----
    k_gemm2<<<N, 64, 0, stream>>>(h, W2, h2, N);
    k_agg2_final<<<N, 64, 0, stream>>>(rowptr, cursor, col, dinv, h2, b2, out, N);
}

// Round 4
// 783.087 us; speedup vs baseline: 2.1259x; 1.0974x over previous
//
#include <hip/hip_runtime.h>
#include <math.h>

#define IN_CH 512
#define HID 128
#define NCLASS 40
#define SCAN_CHUNK 2048
#define FILL_CHUNKS 2048   // edge chunks for range-partitioned fill

typedef __attribute__((ext_vector_type(8))) short short8;
typedef __attribute__((ext_vector_type(4))) float float4v;

static __device__ inline ushort f2bf(float f) {
    unsigned int u = __float_as_uint(f);
    u += 0x7fffu + ((u >> 16) & 1u);
    return (ushort)(u >> 16);
}
static __device__ inline float bf2f(ushort u) {
    return __uint_as_float(((unsigned int)u) << 16);
}

// ---------------- degree count ----------------
__global__ void k_count(const int* __restrict__ dst, int E, int* __restrict__ cnt) {
    int i = blockIdx.x * blockDim.x + threadIdx.x;
    if (i < E) atomicAdd(&cnt[dst[i]], 1);
}

__global__ void k_dinv(const int* __restrict__ cnt, float* __restrict__ dinv, int n) {
    int i = blockIdx.x * blockDim.x + threadIdx.x;
    if (i < n) dinv[i] = rsqrtf((float)cnt[i] + 1.0f);
}

// ---------------- exclusive scan of cnt -> rowptr ----------------
__global__ __launch_bounds__(256) void k_scan_local(const int* __restrict__ cnt,
                                                    int* __restrict__ rowptr,
                                                    int* __restrict__ blocksum, int n) {
    __shared__ int ssum[256];
    int b = blockIdx.x, t = threadIdx.x;
    int base = b * SCAN_CHUNK + t * 8;
    int v[8], s = 0;
    #pragma unroll
    for (int i = 0; i < 8; ++i) {
        int idx = base + i;
        v[i] = (idx < n) ? cnt[idx] : 0;
        s += v[i];
    }
    ssum[t] = s;
    __syncthreads();
    for (int off = 1; off < 256; off <<= 1) {
        int x = (t >= off) ? ssum[t - off] : 0;
        __syncthreads();
        ssum[t] += x;
        __syncthreads();
    }
    int run = ssum[t] - s;
    #pragma unroll
    for (int i = 0; i < 8; ++i) {
        int idx = base + i;
        if (idx < n) rowptr[idx] = run;
        run += v[i];
    }
    if (t == 255) blocksum[b] = ssum[255];
}

__global__ void k_scan_blocksums(int* blocksum, int nb) {
    if (threadIdx.x == 0 && blockIdx.x == 0) {
        int acc = 0;
        for (int i = 0; i < nb; ++i) { int v = blocksum[i]; blocksum[i] = acc; acc += v; }
    }
}

__global__ void k_scan_add(int* __restrict__ rowptr, int* __restrict__ cursor,
                           const int* __restrict__ blocksum, int n) {
    int i = blockIdx.x * blockDim.x + threadIdx.x;
    if (i < n) {
        int r = rowptr[i] + blocksum[i / SCAN_CHUNK];
        rowptr[i] = r;
        cursor[i] = r;
    }
}

// ------- CSR fill, dst-range partitioned: block b -> range b&7, chunk b>>3 ------
// With round-robin workgroup->XCD dispatch, %8 pins each 800KB col window to one
// XCD's L2 so lines fill before write-back (perf heuristic only; correct anyway).
__global__ __launch_bounds__(256) void k_fill(const int* __restrict__ src,
                                              const int* __restrict__ dst,
                                              int* __restrict__ cursor,
                                              int* __restrict__ col, int E, int N) {
    int range = blockIdx.x & 7;
    int chunk = blockIdx.x >> 3;
    int r0 = (N >> 3) * range;
    int r1 = (range == 7) ? N : r0 + (N >> 3);
    int e0 = (int)((long long)E * chunk / FILL_CHUNKS);
    int e1 = (int)((long long)E * (chunk + 1) / FILL_CHUNKS);
    for (int e = e0 + threadIdx.x; e < e1; e += 256) {
        int d = dst[e];
        if (d >= r0 && d < r1) {
            int p = atomicAdd(&cursor[d], 1);
            col[p] = src[e];
        }
    }
}

// ---------------- W1 [512][128] fp32 -> W1t [128][512] bf16 ----------------
__global__ void k_w1t(const float* __restrict__ W1, ushort* __restrict__ W1t) {
    int i = blockIdx.x * blockDim.x + threadIdx.x;
    int n = i >> 9;
    int k = i & 511;
    W1t[i] = f2bf(W1[k * HID + n]);
}

// ------- GEMM1 (MFMA bf16): [M,512] @ [512,128] -> [M,128] bf16 -------
#define GBM 128
#define GBK 64
#define KP 72
__global__ __launch_bounds__(256) void k_gemm1_mfma(const float* __restrict__ X,
                                                    const ushort* __restrict__ W1t,
                                                    ushort* __restrict__ H, int M) {
    __shared__ ushort As[GBM * KP];
    __shared__ ushort Bs[HID * KP];
    int t = threadIdx.x;
    int bm = blockIdx.x * GBM;
    int wave = t >> 6;
    int lane = t & 63;
    int m0w = (wave >> 1) * 64;
    int n0w = (wave & 1) * 64;
    int lrow = lane & 15;
    int quad = lane >> 4;

    float4v acc[4][4];
    #pragma unroll
    for (int i = 0; i < 4; ++i)
        #pragma unroll
        for (int j = 0; j < 4; ++j) acc[i][j] = (float4v)(0.f);

    int ar = t >> 3;
    int ak = (t & 7) * 8;

    for (int k0 = 0; k0 < IN_CH; k0 += GBK) {
        #pragma unroll
        for (int p = 0; p < 4; ++p) {
            int r = ar + 32 * p;
            int gm = bm + r;
            union { ushort u[8]; uint4 v; } pk;
            if (gm < M) {
                const float* gp = &X[(size_t)gm * IN_CH + k0 + ak];
                float4 f0 = *(const float4*)gp;
                float4 f1 = *(const float4*)(gp + 4);
                pk.u[0] = f2bf(f0.x); pk.u[1] = f2bf(f0.y);
                pk.u[2] = f2bf(f0.z); pk.u[3] = f2bf(f0.w);
                pk.u[4] = f2bf(f1.x); pk.u[5] = f2bf(f1.y);
                pk.u[6] = f2bf(f1.z); pk.u[7] = f2bf(f1.w);
            } else {
                pk.v = make_uint4(0, 0, 0, 0);
            }
            *(uint4*)&As[r * KP + ak] = pk.v;
            uint4 bv = *(const uint4*)&W1t[(size_t)r * IN_CH + k0 + ak];
            *(uint4*)&Bs[r * KP + ak] = bv;
        }
        __syncthreads();
        #pragma unroll
        for (int kk = 0; kk < GBK; kk += 32) {
            short8 af[4], bfr[4];
            #pragma unroll
            for (int i = 0; i < 4; ++i)
                af[i] = *(const short8*)&As[(m0w + i * 16 + lrow) * KP + kk + quad * 8];
            #pragma unroll
            for (int j = 0; j < 4; ++j)
                bfr[j] = *(const short8*)&Bs[(n0w + j * 16 + lrow) * KP + kk + quad * 8];
            #pragma unroll
            for (int i = 0; i < 4; ++i)
                #pragma unroll
                for (int j = 0; j < 4; ++j)
                    acc[i][j] = __builtin_amdgcn_mfma_f32_16x16x32_bf16(
                        af[i], bfr[j], acc[i][j], 0, 0, 0);
        }
        __syncthreads();
    }
    #pragma unroll
    for (int i = 0; i < 4; ++i) {
        #pragma unroll
        for (int r = 0; r < 4; ++r) {
            int gm = bm + m0w + i * 16 + quad * 4 + r;
            if (gm < M) {
                #pragma unroll
                for (int j = 0; j < 4; ++j)
                    H[(size_t)gm * HID + n0w + j * 16 + lrow] = f2bf(acc[i][j][r]);
            }
        }
    }
}

// ------- layer-1 aggregation (bf16 gather) + self-loop + bias + relu -> bf16 ----
__global__ __launch_bounds__(64) void k_agg1(const int* __restrict__ rowptr,
                                             const int* __restrict__ rowend,
                                             const int* __restrict__ col,
                                             const float* __restrict__ dinv,
                                             const unsigned int* __restrict__ h1b,
                                             const float* __restrict__ b1,
                                             unsigned int* __restrict__ hb, int N) {
    int m = blockIdx.x;
    int t = threadIdx.x;   // lane t owns channels {2t, 2t+1}
    float dm = dinv[m];
    unsigned int sv = h1b[(size_t)m * 64 + t];
    float sw = dm * dm;
    float ax = bf2f((ushort)(sv & 0xffff)) * sw;
    float ay = bf2f((ushort)(sv >> 16)) * sw;
    int jend = rowend[m];
    for (int j = rowptr[m]; j < jend; ++j) {
        int s = col[j];
        float nrm = dinv[s] * dm;
        unsigned int v = h1b[(size_t)s * 64 + t];
        ax += bf2f((ushort)(v & 0xffff)) * nrm;
        ay += bf2f((ushort)(v >> 16)) * nrm;
    }
    float2 bb = ((const float2*)b1)[t];
    ax = fmaxf(ax + bb.x, 0.f);
    ay = fmaxf(ay + bb.y, 0.f);
    hb[(size_t)m * 64 + t] = (unsigned int)f2bf(ax) | ((unsigned int)f2bf(ay) << 16);
}

// ------- GEMM2: [M,128]bf16 @ [128,40]fp32 -> [M,40] bf16 -------
__global__ __launch_bounds__(64) void k_gemm2(const unsigned int* __restrict__ Hin,
                                              const float* __restrict__ W2,
                                              ushort* __restrict__ H2, int M) {
    __shared__ float hs[HID];
    int m = blockIdx.x;
    int t = threadIdx.x;
    unsigned int v = Hin[(size_t)m * 64 + t];
    hs[2 * t]     = bf2f((ushort)(v & 0xffff));
    hs[2 * t + 1] = bf2f((ushort)(v >> 16));
    __syncthreads();
    if (t < NCLASS) {
        float acc = 0.f;
        #pragma unroll 8
        for (int k = 0; k < HID; ++k) acc += hs[k] * W2[k * NCLASS + t];
        H2[(size_t)m * NCLASS + t] = f2bf(acc);
    }
}

// ------- layer-2 aggregation (bf16 gather) + self-loop + bias + log_softmax ----
__global__ __launch_bounds__(64) void k_agg2_final(const int* __restrict__ rowptr,
                                                   const int* __restrict__ rowend,
                                                   const int* __restrict__ col,
                                                   const float* __restrict__ dinv,
                                                   const ushort* __restrict__ h2b,
                                                   const float* __restrict__ b2,
                                                   float* __restrict__ out, int N) {
    int m = blockIdx.x;
    int t = threadIdx.x;
    float dm = dinv[m];
    float val = 0.f;
    if (t < NCLASS) val = bf2f(h2b[(size_t)m * NCLASS + t]) * dm * dm;
    int jend = rowend[m];
    for (int j = rowptr[m]; j < jend; ++j) {
        int s = col[j];
        float nrm = dinv[s] * dm;
        if (t < NCLASS) val += bf2f(h2b[(size_t)s * NCLASS + t]) * nrm;
    }
    if (t < NCLASS) val += b2[t];
    float v = (t < NCLASS) ? val : -INFINITY;
    #pragma unroll
    for (int off = 32; off; off >>= 1) v = fmaxf(v, __shfl_xor(v, off));
    float ex = (t < NCLASS) ? expf(val - v) : 0.f;
    #pragma unroll
    for (int off = 32; off; off >>= 1) ex += __shfl_xor(ex, off);
    float lse = v + logf(ex);
    if (t < NCLASS) out[(size_t)m * NCLASS + t] = val - lse;
}

extern "C" void kernel_launch(void* const* d_in, const int* in_sizes, int n_in,
                              void* d_out, int out_size, void* d_ws, size_t ws_size,
                              hipStream_t stream) {
    const float* x  = (const float*)d_in[0];
    const int*   ei = (const int*)d_in[1];
    const float* W1 = (const float*)d_in[2];
    const float* b1 = (const float*)d_in[3];
    const float* W2 = (const float*)d_in[4];
    const float* b2 = (const float*)d_in[5];
    float* out = (float*)d_out;

    const int N = in_sizes[0] / IN_CH;   // 100000
    const int E = in_sizes[1] / 2;       // 1600000
    const int* src = ei;
    const int* dst = ei + E;

    const int NB_SCAN = (N + SCAN_CHUNK - 1) / SCAN_CHUNK;

    // workspace layout (4-byte words)
    size_t Npad = ((size_t)N + 127) / 128 * 128;
    float* ws = (float*)d_ws;
    float* dinv    = ws;                          // N floats
    int*   cnt     = (int*)(ws + Npad);           // N ints
    int*   rowptr  = (int*)(ws + 2 * Npad);       // N ints
    int*   cursor  = (int*)(ws + 3 * Npad);       // N ints (becomes row end)
    int*   bsum    = (int*)(ws + 4 * Npad);       // <=128 ints
    int*   col     = (int*)(ws + 4 * Npad + 128); // E ints
    size_t o_h1    = 4 * Npad + 128 + (size_t)E;
    unsigned int* h1b = (unsigned int*)(ws + o_h1);             // N*64 words (bf16x2)
    unsigned int* hb  = (unsigned int*)(ws + o_h1 + (size_t)N * 64); // N*64 words
    ushort* h2b    = (ushort*)h1b;                // reuse (h1b dead after agg1)
    ushort* W1t    = (ushort*)hb;                 // 128KB, dead before agg1 writes hb

    // ---- CSR build ----
    hipMemsetAsync(cnt, 0, (size_t)N * sizeof(int), stream);
    k_count<<<(E + 255) / 256, 256, 0, stream>>>(dst, E, cnt);
    k_dinv<<<(N + 255) / 256, 256, 0, stream>>>(cnt, dinv, N);
    k_scan_local<<<NB_SCAN, 256, 0, stream>>>(cnt, rowptr, bsum, N);
    k_scan_blocksums<<<1, 64, 0, stream>>>(bsum, NB_SCAN);
    k_scan_add<<<(N + 255) / 256, 256, 0, stream>>>(rowptr, cursor, bsum, N);
    k_fill<<<8 * FILL_CHUNKS, 256, 0, stream>>>(src, dst, cursor, col, E, N);

    // ---- layer 1 ----
    k_w1t<<<(HID * IN_CH) / 256, 256, 0, stream>>>(W1, W1t);
    k_gemm1_mfma<<<(N + GBM - 1) / GBM, 256, 0, stream>>>(x, W1t, (ushort*)h1b, N);
    k_agg1<<<N, 64, 0, stream>>>(rowptr, cursor, col, dinv, h1b, b1, hb, N);

    // ---- layer 2 ----
    k_gemm2<<<N, 64, 0, stream>>>(hb, W2, h2b, N);
    k_agg2_final<<<N, 64, 0, stream>>>(rowptr, cursor, col, dinv, h2b, b2, out, N);
}

// Round 5
// 769.540 us; speedup vs baseline: 2.1634x; 1.0176x over previous
//
#include <hip/hip_runtime.h>
#include <math.h>

#define IN_CH 512
#define HID 128
#define NCLASS 40
#define SCAN_CHUNK 2048
#define FILL_CHUNKS 2048   // edge chunks for range-partitioned fill

typedef __attribute__((ext_vector_type(8))) short short8;
typedef __attribute__((ext_vector_type(4))) float float4v;

static __device__ inline ushort f2bf(float f) {
    unsigned int u = __float_as_uint(f);
    u += 0x7fffu + ((u >> 16) & 1u);
    return (ushort)(u >> 16);
}
static __device__ inline float bf2f(ushort u) {
    return __uint_as_float(((unsigned int)u) << 16);
}

// ---------------- degree count ----------------
__global__ void k_count(const int* __restrict__ dst, int E, int* __restrict__ cnt) {
    int i = blockIdx.x * blockDim.x + threadIdx.x;
    if (i < E) atomicAdd(&cnt[dst[i]], 1);
}

__global__ void k_dinv(const int* __restrict__ cnt, float* __restrict__ dinv, int n) {
    int i = blockIdx.x * blockDim.x + threadIdx.x;
    if (i < n) dinv[i] = rsqrtf((float)cnt[i] + 1.0f);
}

// ---------------- exclusive scan of cnt -> rowptr ----------------
__global__ __launch_bounds__(256) void k_scan_local(const int* __restrict__ cnt,
                                                    int* __restrict__ rowptr,
                                                    int* __restrict__ blocksum, int n) {
    __shared__ int ssum[256];
    int b = blockIdx.x, t = threadIdx.x;
    int base = b * SCAN_CHUNK + t * 8;
    int v[8], s = 0;
    #pragma unroll
    for (int i = 0; i < 8; ++i) {
        int idx = base + i;
        v[i] = (idx < n) ? cnt[idx] : 0;
        s += v[i];
    }
    ssum[t] = s;
    __syncthreads();
    for (int off = 1; off < 256; off <<= 1) {
        int x = (t >= off) ? ssum[t - off] : 0;
        __syncthreads();
        ssum[t] += x;
        __syncthreads();
    }
    int run = ssum[t] - s;
    #pragma unroll
    for (int i = 0; i < 8; ++i) {
        int idx = base + i;
        if (idx < n) rowptr[idx] = run;
        run += v[i];
    }
    if (t == 255) blocksum[b] = ssum[255];
}

__global__ void k_scan_blocksums(int* blocksum, int nb) {
    if (threadIdx.x == 0 && blockIdx.x == 0) {
        int acc = 0;
        for (int i = 0; i < nb; ++i) { int v = blocksum[i]; blocksum[i] = acc; acc += v; }
    }
}

__global__ void k_scan_add(int* __restrict__ rowptr, int* __restrict__ cursor,
                           const int* __restrict__ blocksum, int n) {
    int i = blockIdx.x * blockDim.x + threadIdx.x;
    if (i < n) {
        int r = rowptr[i] + blocksum[i / SCAN_CHUNK];
        rowptr[i] = r;
        cursor[i] = r;
    }
}

// ------- CSR fill, dst-range partitioned for L2 locality ----------
__global__ __launch_bounds__(256) void k_fill(const int* __restrict__ src,
                                              const int* __restrict__ dst,
                                              int* __restrict__ cursor,
                                              int* __restrict__ col, int E, int N) {
    int range = blockIdx.x & 7;
    int chunk = blockIdx.x >> 3;
    int r0 = (N >> 3) * range;
    int r1 = (range == 7) ? N : r0 + (N >> 3);
    int e0 = (int)((long long)E * chunk / FILL_CHUNKS);
    int e1 = (int)((long long)E * (chunk + 1) / FILL_CHUNKS);
    for (int e = e0 + threadIdx.x; e < e1; e += 256) {
        int d = dst[e];
        if (d >= r0 && d < r1) {
            int p = atomicAdd(&cursor[d], 1);
            col[p] = src[e];
        }
    }
}

// ---------------- W1 [512][128] fp32 -> W1t [128][512] bf16 ----------------
__global__ void k_w1t(const float* __restrict__ W1, ushort* __restrict__ W1t) {
    int i = blockIdx.x * blockDim.x + threadIdx.x;
    int n = i >> 9;
    int k = i & 511;
    W1t[i] = f2bf(W1[k * HID + n]);
}

// ------- GEMM1 (MFMA bf16): [M,512] @ [512,128] -> [M,128] bf16 -------
// A staged via VGPR prefetch -> LDS (fp32->bf16 cvt in-flight);
// B fragments read directly from L2-hot W1t (128 KB, resident on every XCD).
#define GBM 128
#define GBK 64
#define KP 72    // LDS row stride (bf16): 144 B -> worst 2-way bank aliasing (free)
__global__ __launch_bounds__(256) void k_gemm1_mfma(const float* __restrict__ X,
                                                    const ushort* __restrict__ W1t,
                                                    ushort* __restrict__ H, int M) {
    __shared__ ushort As[GBM * KP];   // 18.4 KB
    int t = threadIdx.x;
    int bm = blockIdx.x * GBM;
    int wave = t >> 6;
    int lane = t & 63;
    int m0w = (wave >> 1) * 64;
    int n0w = (wave & 1) * 64;
    int lrow = lane & 15;
    int quad = lane >> 4;

    float4v acc[4][4];
    #pragma unroll
    for (int i = 0; i < 4; ++i)
        #pragma unroll
        for (int j = 0; j < 4; ++j) acc[i][j] = (float4v)(0.f);

    // staging assignment: thread t covers row ar, fp32 cols [ah, ah+32)
    int ar = t >> 1;
    int ah = (t & 1) * 32;
    int gmr = bm + ar;
    if (gmr >= M) gmr = M - 1;        // clamp: OOB C rows are never written
    const float* gA = &X[(size_t)gmr * IN_CH + ah];

    // prefetch iter 0 into registers (8 x float4 = 128 B/thread)
    float4 pre[8];
    #pragma unroll
    for (int i = 0; i < 8; ++i) pre[i] = *(const float4*)(gA + i * 4);

    for (int k0 = 0; k0 < IN_CH; k0 += GBK) {
        // convert prefetched fp32 -> bf16, store to LDS
        #pragma unroll
        for (int i = 0; i < 4; ++i) {
            union { ushort u[8]; uint4 v; } pk;
            float4 f0 = pre[2 * i], f1 = pre[2 * i + 1];
            pk.u[0] = f2bf(f0.x); pk.u[1] = f2bf(f0.y);
            pk.u[2] = f2bf(f0.z); pk.u[3] = f2bf(f0.w);
            pk.u[4] = f2bf(f1.x); pk.u[5] = f2bf(f1.y);
            pk.u[6] = f2bf(f1.z); pk.u[7] = f2bf(f1.w);
            *(uint4*)&As[ar * KP + ah + i * 8] = pk.v;
        }
        // issue next iter's global loads before the barrier; they complete
        // under the MFMA phase (plain VGPR loads: no drain at s_barrier)
        if (k0 + GBK < IN_CH) {
            #pragma unroll
            for (int i = 0; i < 8; ++i)
                pre[i] = *(const float4*)(gA + k0 + GBK + i * 4);
        }
        __syncthreads();
        #pragma unroll
        for (int kk = 0; kk < GBK; kk += 32) {
            short8 af[4], bfr[4];
            #pragma unroll
            for (int j = 0; j < 4; ++j)
                bfr[j] = *(const short8*)&W1t[(size_t)(n0w + j * 16 + lrow) * IN_CH
                                              + k0 + kk + quad * 8];
            #pragma unroll
            for (int i = 0; i < 4; ++i)
                af[i] = *(const short8*)&As[(m0w + i * 16 + lrow) * KP + kk + quad * 8];
            #pragma unroll
            for (int i = 0; i < 4; ++i)
                #pragma unroll
                for (int j = 0; j < 4; ++j)
                    acc[i][j] = __builtin_amdgcn_mfma_f32_16x16x32_bf16(
                        af[i], bfr[j], acc[i][j], 0, 0, 0);
        }
        __syncthreads();
    }
    #pragma unroll
    for (int i = 0; i < 4; ++i) {
        #pragma unroll
        for (int r = 0; r < 4; ++r) {
            int gm = bm + m0w + i * 16 + quad * 4 + r;
            if (gm < M) {
                #pragma unroll
                for (int j = 0; j < 4; ++j)
                    H[(size_t)gm * HID + n0w + j * 16 + lrow] = f2bf(acc[i][j][r]);
            }
        }
    }
}

// ------- layer-1 aggregation (bf16 gather) + self-loop + bias + relu -> bf16 ----
__global__ __launch_bounds__(64) void k_agg1(const int* __restrict__ rowptr,
                                             const int* __restrict__ rowend,
                                             const int* __restrict__ col,
                                             const float* __restrict__ dinv,
                                             const unsigned int* __restrict__ h1b,
                                             const float* __restrict__ b1,
                                             unsigned int* __restrict__ hb, int N) {
    int m = blockIdx.x;
    int t = threadIdx.x;   // lane t owns channels {2t, 2t+1}
    float dm = dinv[m];
    unsigned int sv = h1b[(size_t)m * 64 + t];
    float sw = dm * dm;
    float ax = bf2f((ushort)(sv & 0xffff)) * sw;
    float ay = bf2f((ushort)(sv >> 16)) * sw;
    int jend = rowend[m];
    for (int j = rowptr[m]; j < jend; ++j) {
        int s = col[j];
        float nrm = dinv[s] * dm;
        unsigned int v = h1b[(size_t)s * 64 + t];
        ax += bf2f((ushort)(v & 0xffff)) * nrm;
        ay += bf2f((ushort)(v >> 16)) * nrm;
    }
    float2 bb = ((const float2*)b1)[t];
    ax = fmaxf(ax + bb.x, 0.f);
    ay = fmaxf(ay + bb.y, 0.f);
    hb[(size_t)m * 64 + t] = (unsigned int)f2bf(ax) | ((unsigned int)f2bf(ay) << 16);
}

// ------- GEMM2: [M,128]bf16 @ [128,40]fp32 -> [M,40] bf16 -------
__global__ __launch_bounds__(64) void k_gemm2(const unsigned int* __restrict__ Hin,
                                              const float* __restrict__ W2,
                                              ushort* __restrict__ H2, int M) {
    __shared__ float hs[HID];
    int m = blockIdx.x;
    int t = threadIdx.x;
    unsigned int v = Hin[(size_t)m * 64 + t];
    hs[2 * t]     = bf2f((ushort)(v & 0xffff));
    hs[2 * t + 1] = bf2f((ushort)(v >> 16));
    __syncthreads();
    if (t < NCLASS) {
        float acc = 0.f;
        #pragma unroll 8
        for (int k = 0; k < HID; ++k) acc += hs[k] * W2[k * NCLASS + t];
        H2[(size_t)m * NCLASS + t] = f2bf(acc);
    }
}

// ------- layer-2 aggregation (bf16 gather) + self-loop + bias + log_softmax ----
__global__ __launch_bounds__(64) void k_agg2_final(const int* __restrict__ rowptr,
                                                   const int* __restrict__ rowend,
                                                   const int* __restrict__ col,
                                                   const float* __restrict__ dinv,
                                                   const ushort* __restrict__ h2b,
                                                   const float* __restrict__ b2,
                                                   float* __restrict__ out, int N) {
    int m = blockIdx.x;
    int t = threadIdx.x;
    float dm = dinv[m];
    float val = 0.f;
    if (t < NCLASS) val = bf2f(h2b[(size_t)m * NCLASS + t]) * dm * dm;
    int jend = rowend[m];
    for (int j = rowptr[m]; j < jend; ++j) {
        int s = col[j];
        float nrm = dinv[s] * dm;
        if (t < NCLASS) val += bf2f(h2b[(size_t)s * NCLASS + t]) * nrm;
    }
    if (t < NCLASS) val += b2[t];
    float v = (t < NCLASS) ? val : -INFINITY;
    #pragma unroll
    for (int off = 32; off; off >>= 1) v = fmaxf(v, __shfl_xor(v, off));
    float ex = (t < NCLASS) ? expf(val - v) : 0.f;
    #pragma unroll
    for (int off = 32; off; off >>= 1) ex += __shfl_xor(ex, off);
    float lse = v + logf(ex);
    if (t < NCLASS) out[(size_t)m * NCLASS + t] = val - lse;
}

extern "C" void kernel_launch(void* const* d_in, const int* in_sizes, int n_in,
                              void* d_out, int out_size, void* d_ws, size_t ws_size,
                              hipStream_t stream) {
    const float* x  = (const float*)d_in[0];
    const int*   ei = (const int*)d_in[1];
    const float* W1 = (const float*)d_in[2];
    const float* b1 = (const float*)d_in[3];
    const float* W2 = (const float*)d_in[4];
    const float* b2 = (const float*)d_in[5];
    float* out = (float*)d_out;

    const int N = in_sizes[0] / IN_CH;   // 100000
    const int E = in_sizes[1] / 2;       // 1600000
    const int* src = ei;
    const int* dst = ei + E;

    const int NB_SCAN = (N + SCAN_CHUNK - 1) / SCAN_CHUNK;

    // workspace layout (4-byte words)
    size_t Npad = ((size_t)N + 127) / 128 * 128;
    float* ws = (float*)d_ws;
    float* dinv    = ws;                          // N floats
    int*   cnt     = (int*)(ws + Npad);           // N ints
    int*   rowptr  = (int*)(ws + 2 * Npad);       // N ints
    int*   cursor  = (int*)(ws + 3 * Npad);       // N ints (becomes row end)
    int*   bsum    = (int*)(ws + 4 * Npad);       // <=128 ints
    int*   col     = (int*)(ws + 4 * Npad + 128); // E ints
    size_t o_h1    = 4 * Npad + 128 + (size_t)E;
    unsigned int* h1b = (unsigned int*)(ws + o_h1);                  // N*64 words
    unsigned int* hb  = (unsigned int*)(ws + o_h1 + (size_t)N * 64); // N*64 words
    ushort* h2b    = (ushort*)h1b;                // reuse (h1b dead after agg1)
    ushort* W1t    = (ushort*)hb;                 // 128KB, dead before agg1 writes hb

    // ---- CSR build ----
    hipMemsetAsync(cnt, 0, (size_t)N * sizeof(int), stream);
    k_count<<<(E + 255) / 256, 256, 0, stream>>>(dst, E, cnt);
    k_dinv<<<(N + 255) / 256, 256, 0, stream>>>(cnt, dinv, N);
    k_scan_local<<<NB_SCAN, 256, 0, stream>>>(cnt, rowptr, bsum, N);
    k_scan_blocksums<<<1, 64, 0, stream>>>(bsum, NB_SCAN);
    k_scan_add<<<(N + 255) / 256, 256, 0, stream>>>(rowptr, cursor, bsum, N);
    k_fill<<<8 * FILL_CHUNKS, 256, 0, stream>>>(src, dst, cursor, col, E, N);

    // ---- layer 1 ----
    k_w1t<<<(HID * IN_CH) / 256, 256, 0, stream>>>(W1, W1t);
    k_gemm1_mfma<<<(N + GBM - 1) / GBM, 256, 0, stream>>>(x, W1t, (ushort*)h1b, N);
    k_agg1<<<N, 64, 0, stream>>>(rowptr, cursor, col, dinv, h1b, b1, hb, N);

    // ---- layer 2 ----
    k_gemm2<<<N, 64, 0, stream>>>(hb, W2, h2b, N);
    k_agg2_final<<<N, 64, 0, stream>>>(rowptr, cursor, col, dinv, h2b, b2, out, N);
}